// Round 7
// baseline (611.708 us; speedup 1.0000x reference)
//
#include <hip/hip_runtime.h>

#define DDIM  2048
#define KC    8
#define TPB_A 16          // tokens per block, k_assign (4 waves x 4 tokens)
#define TPB_C 16          // tokens per block, k_final

typedef float nfloat4 __attribute__((ext_vector_type(4)));
typedef unsigned short ushortv8 __attribute__((ext_vector_type(8)));
typedef unsigned short ushortv4 __attribute__((ext_vector_type(4)));

__device__ __forceinline__ void nt_store4(const float4& v, float* p){
  nfloat4 nv; nv.x = v.x; nv.y = v.y; nv.z = v.z; nv.w = v.w;
  __builtin_nontemporal_store(nv, (nfloat4*)p);
}
__device__ __forceinline__ void nt_store_us4(const ushortv4& v, unsigned short* p){
  __builtin_nontemporal_store(v, (ushortv4*)p);
}
__device__ __forceinline__ ushortv8 nt_load_us8(const unsigned short* p){
  return __builtin_nontemporal_load((const ushortv8*)p);
}

// bf16 round-to-nearest-even pack; unpack = shift (exact)
__device__ __forceinline__ unsigned short f2bf(float f){
  unsigned u = __float_as_uint(f);
  u += 0x7fffu + ((u >> 16) & 1u);
  return (unsigned short)(u >> 16);
}
__device__ __forceinline__ float bf2f(unsigned short h){
  return __uint_as_float(((unsigned)h) << 16);
}
__device__ __forceinline__ float bflo(unsigned u){ return __uint_as_float(u << 16); }
__device__ __forceinline__ float bfhi(unsigned u){ return __uint_as_float(u & 0xffff0000u); }

__device__ __forceinline__ float wave_sum(float v){
  #pragma unroll
  for (int off = 32; off > 0; off >>= 1)
    v += __shfl_xor(v, off, 64);
  return v;   // broadcast
}

// Multi-value butterfly: sum v[0..7] across 64 lanes in 10 shuffles.
// On exit EVERY lane l holds the full wave-sum for cluster
// k = 4*(l&1) + 2*((l>>1)&1) + ((l>>2)&1).
__device__ __forceinline__ float butterfly8(float v[8], int t){
  {
    const bool h = (t & 1);
    #pragma unroll
    for (int j = 0; j < 4; ++j){
      float s    = h ? v[j]   : v[j+4];
      float keep = h ? v[j+4] : v[j];
      v[j] = keep + __shfl_xor(s, 1, 64);
    }
  }
  {
    const bool h = (t & 2);
    #pragma unroll
    for (int j = 0; j < 2; ++j){
      float s    = h ? v[j]   : v[j+2];
      float keep = h ? v[j+2] : v[j];
      v[j] = keep + __shfl_xor(s, 2, 64);
    }
  }
  {
    const bool h = (t & 4);
    float s    = h ? v[0] : v[1];
    float keep = h ? v[1] : v[0];
    v[0] = keep + __shfl_xor(s, 4, 64);
  }
  v[0] += __shfl_xor(v[0], 8, 64);
  v[0] += __shfl_xor(v[0], 16, 64);
  v[0] += __shfl_xor(v[0], 32, 64);
  return v[0];
}

// argmax over the 8 per-cluster sums left by butterfly8 (first-index ties)
__device__ __forceinline__ int argmax8(float bv, int lane){
  int bi = ((lane&1)<<2) | (lane&2) | ((lane>>2)&1);
  #pragma unroll
  for (int off = 1; off < 8; off <<= 1){
    float ov = __shfl_xor(bv, off, 64);
    int   oi = __shfl_xor(bi, off, 64);
    if (ov > bv || (ov == bv && oi < bi)){ bv = ov; bi = oi; }
  }
  return bi;
}

__device__ __forceinline__ float gelu_tanh(float v){
  const float c = 0.7978845608028654f;
  float tt = c * v * (1.0f + 0.044715f * v * v);
  float e  = __expf(2.0f * tt);
  float th = 1.0f - 2.0f / (e + 1.0f);
  return 0.5f * v * (1.0f + th);
}

// ---------------------------------------------------------------------------
// k_assign: prologue normalizes prototypes (fp32 proto -> bf16 LDS);
// stage 1 = wave-per-token argmax, SMALL live set (X[8]+va[8] ~ 55 VGPR,
// no prefetch array, no sched_barrier -> provably no spill; latency hidden
// by 16 waves/CU TLP); stage 2 = thread-per-8-dims segment accumulate,
// nt bf16 partial stores.
// ---------------------------------------------------------------------------
__global__ __launch_bounds__(256, 4)
void k_assign(const float* __restrict__ x, const float* __restrict__ proto,
              unsigned short* __restrict__ part, float* __restrict__ pcnts, int ntok)
{
  __shared__ unsigned short Pl[KC*DDIM];   // 32 KB bf16 normalized prototypes
  __shared__ float rednorm[4*KC];
  __shared__ float sInv[KC];
  __shared__ int   asg[TPB_A];

  const int t = threadIdx.x;
  const int wave = t >> 6, lane = t & 63;
  const int d0 = 4*t, d1 = 1024 + 4*t;

  // ---- prologue: P_hat = proto / max(||proto||,1e-12), packed bf16 to LDS ----
  {
    float4 Q0[KC], Q1[KC];
    #pragma unroll
    for (int k = 0; k < KC; ++k){
      Q0[k] = *(const float4*)(proto + k*DDIM + d0);
      Q1[k] = *(const float4*)(proto + k*DDIM + d1);
    }
    #pragma unroll
    for (int k = 0; k < KC; ++k){
      float ss = Q0[k].x*Q0[k].x + Q0[k].y*Q0[k].y + Q0[k].z*Q0[k].z + Q0[k].w*Q0[k].w
               + Q1[k].x*Q1[k].x + Q1[k].y*Q1[k].y + Q1[k].z*Q1[k].z + Q1[k].w*Q1[k].w;
      ss = wave_sum(ss);
      if (lane == 0) rednorm[wave*KC + k] = ss;
    }
    __syncthreads();
    if (t < KC){
      float ss = rednorm[t] + rednorm[KC+t] + rednorm[2*KC+t] + rednorm[3*KC+t];
      sInv[t] = 1.0f / fmaxf(sqrtf(ss), 1e-12f);
    }
    __syncthreads();
    #pragma unroll
    for (int k = 0; k < KC; ++k){
      const float inv = sInv[k];
      ushortv4 o0, o1;
      o0[0]=f2bf(Q0[k].x*inv); o0[1]=f2bf(Q0[k].y*inv); o0[2]=f2bf(Q0[k].z*inv); o0[3]=f2bf(Q0[k].w*inv);
      o1[0]=f2bf(Q1[k].x*inv); o1[1]=f2bf(Q1[k].y*inv); o1[2]=f2bf(Q1[k].z*inv); o1[3]=f2bf(Q1[k].w*inv);
      *(ushortv4*)(Pl + k*DDIM + d0) = o0;
      *(ushortv4*)(Pl + k*DDIM + d1) = o1;
    }
  }
  __syncthreads();

  const int tok_base = blockIdx.x * TPB_A;
  const unsigned* Pw = (const unsigned*)Pl;

  // ---- stage 1: wave w -> tokens w*4 .. w*4+3, minimal live set ----
  {
    const int tl0 = wave*4;
    #pragma unroll
    for (int i = 0; i < 4; ++i){
      const int tok = tok_base + tl0 + i;
      if (tok < ntok){
        const float* xp = x + (size_t)tok*DDIM + 4*lane;
        float4 X[8];
        #pragma unroll
        for (int j = 0; j < 8; ++j)
          X[j] = *(const float4*)(xp + j*256);
        float va[KC];
        #pragma unroll
        for (int k = 0; k < KC; ++k) va[k] = 0.f;
        #pragma unroll
        for (int j = 0; j < 8; ++j){
          #pragma unroll
          for (int k = 0; k < KC; ++k){
            uint2 u = *(const uint2*)(Pw + k*1024 + j*128 + 2*lane);
            va[k] += X[j].x*bflo(u.x) + X[j].y*bfhi(u.x)
                   + X[j].z*bflo(u.y) + X[j].w*bfhi(u.y);
          }
        }
        float bv = butterfly8(va, lane);
        int bi = argmax8(bv, lane);
        if (lane == 0) asg[tl0 + i] = bi;
      }
    }
  }
  __syncthreads();

  // ---- stage 2: thread t owns dims {4t..4t+3, 1024+4t..+3}; x re-read L2-hot ----
  float4 acc0[KC], acc1[KC];
  float cnt[KC];
  #pragma unroll
  for (int k = 0; k < KC; ++k){
    acc0[k] = make_float4(0.f,0.f,0.f,0.f);
    acc1[k] = make_float4(0.f,0.f,0.f,0.f);
    cnt[k] = 0.f;
  }
  #pragma unroll
  for (int i = 0; i < TPB_A; ++i){
    const int tok = tok_base + i;
    if (tok < ntok){
      const int a = __builtin_amdgcn_readfirstlane(asg[i]);   // block-uniform -> scalar branch
      float4 xa = *(const float4*)(x + (size_t)tok*DDIM + d0);
      float4 xb = *(const float4*)(x + (size_t)tok*DDIM + d1);
      #pragma unroll
      for (int k = 0; k < KC; ++k){
        if (a == k){
          acc0[k].x += xa.x; acc0[k].y += xa.y; acc0[k].z += xa.z; acc0[k].w += xa.w;
          acc1[k].x += xb.x; acc1[k].y += xb.y; acc1[k].z += xb.z; acc1[k].w += xb.w;
          cnt[k] += 1.f;
        }
      }
    }
  }
  // nt stores: part is write-once/read-once — keep it out of L3 so x stays resident
  unsigned short* dst = part + (size_t)blockIdx.x * (KC*DDIM);
  #pragma unroll
  for (int k = 0; k < KC; ++k){
    ushortv4 o0, o1;
    o0[0]=f2bf(acc0[k].x); o0[1]=f2bf(acc0[k].y); o0[2]=f2bf(acc0[k].z); o0[3]=f2bf(acc0[k].w);
    o1[0]=f2bf(acc1[k].x); o1[1]=f2bf(acc1[k].y); o1[2]=f2bf(acc1[k].z); o1[3]=f2bf(acc1[k].w);
    nt_store_us4(o0, dst + k*DDIM + d0);
    nt_store_us4(o1, dst + k*DDIM + d1);
  }
  if (t == 0){
    #pragma unroll
    for (int k = 0; k < KC; ++k) pcnts[blockIdx.x*KC + k] = cnt[k];
  }
}

// ---------------------------------------------------------------------------
// k_reduce: single-stage — nbA bf16 partials -> fp32 column sums (+ counts).
// grid = 256: block (k = bid>>5, s = bid&31) owns a 64-dim slice of cluster k.
// 32 thread-groups each sum a b-stripe; LDS combine; 64 threads finalize.
// ---------------------------------------------------------------------------
__global__ __launch_bounds__(256)
void k_reduce(const unsigned short* __restrict__ part, const float* __restrict__ pcnts,
              float* __restrict__ csum, float* __restrict__ ccnt, int nbA)
{
  const int k = blockIdx.x >> 5;       // 0..7
  const int s = blockIdx.x & 31;       // 0..31
  const int t = threadIdx.x;
  const int slot = t & 7;              // 8 x 8-elem slots cover the 64-dim slice
  const int grp  = t >> 3;             // 32 b-stripes

  __shared__ float cmb[32][8][8];      // [grp][slot][j] = 8 KB
  __shared__ float credn[4];

  const size_t ebase = (size_t)k*DDIM + s*64 + slot*8;
  float a[8] = {0.f,0.f,0.f,0.f,0.f,0.f,0.f,0.f};
  for (int b = grp; b < nbA; b += 32){
    ushortv8 v = nt_load_us8(part + (size_t)b*(KC*DDIM) + ebase);
    #pragma unroll
    for (int j = 0; j < 8; ++j) a[j] += bf2f(v[j]);
  }
  #pragma unroll
  for (int j = 0; j < 8; ++j) cmb[grp][slot][j] = a[j];

  // counts (only s==0 blocks)
  float c = 0.f;
  if (s == 0){
    for (int b = t; b < nbA; b += 256) c += pcnts[b*KC + k];
    c = wave_sum(c);
    if ((t & 63) == 0) credn[t >> 6] = c;
  }
  __syncthreads();

  if (t < 64){
    const int slot2 = t >> 3, j = t & 7;
    float sum = 0.f;
    #pragma unroll
    for (int g = 0; g < 32; ++g) sum += cmb[g][slot2][j];
    csum[(size_t)k*DDIM + s*64 + slot2*8 + j] = sum;
  }
  if (s == 0 && t == 0)
    ccnt[k] = credn[0] + credn[1] + credn[2] + credn[3];
}

// ---------------------------------------------------------------------------
// k_mid: csum -> centroid (count>0 else proto) -> normalize(1e-12) -> momentum
// -> normalize(1e-8) -> p2n bf16.  Block = cluster.
// ---------------------------------------------------------------------------
__global__ __launch_bounds__(256)
void k_mid(const float* __restrict__ csum, const float* __restrict__ ccnt,
           const float* __restrict__ proto, unsigned short* __restrict__ p2nbf)
{
  const int k = blockIdx.x, t = threadIdx.x;
  const int wave = t >> 6, lane = t & 63;
  __shared__ float s1[4], s2[4];
  const int d0 = 4*t, d1 = 1024 + 4*t;

  float4 a = *(const float4*)(csum + k*DDIM + d0);
  float4 b = *(const float4*)(csum + k*DDIM + d1);
  const float c = ccnt[k];

  float4 pr0 = *(const float4*)(proto + k*DDIM + d0);
  float4 pr1 = *(const float4*)(proto + k*DDIM + d1);

  float4 c0, c1;
  if (c > 0.f){
    const float inv = 1.0f / fmaxf(c, 1.0f);
    c0.x=a.x*inv; c0.y=a.y*inv; c0.z=a.z*inv; c0.w=a.w*inv;
    c1.x=b.x*inv; c1.y=b.y*inv; c1.z=b.z*inv; c1.w=b.w*inv;
  } else { c0 = pr0; c1 = pr1; }

  float ss = c0.x*c0.x + c0.y*c0.y + c0.z*c0.z + c0.w*c0.w
           + c1.x*c1.x + c1.y*c1.y + c1.z*c1.z + c1.w*c1.w;
  ss = wave_sum(ss);
  if (lane == 0) s1[wave] = ss;
  __syncthreads();
  ss = s1[0] + s1[1] + s1[2] + s1[3];
  const float invc = 1.0f / fmaxf(sqrtf(ss), 1e-12f);

  const float m = 0.999f, om = 1.0f - 0.999f;
  float4 p20, p21;
  p20.x = m*pr0.x + om*c0.x*invc; p20.y = m*pr0.y + om*c0.y*invc;
  p20.z = m*pr0.z + om*c0.z*invc; p20.w = m*pr0.w + om*c0.w*invc;
  p21.x = m*pr1.x + om*c1.x*invc; p21.y = m*pr1.y + om*c1.y*invc;
  p21.z = m*pr1.z + om*c1.z*invc; p21.w = m*pr1.w + om*c1.w*invc;

  float ss2 = p20.x*p20.x + p20.y*p20.y + p20.z*p20.z + p20.w*p20.w
            + p21.x*p21.x + p21.y*p21.y + p21.z*p21.z + p21.w*p21.w;
  ss2 = wave_sum(ss2);
  if (lane == 0) s2[wave] = ss2;
  __syncthreads();
  ss2 = s2[0] + s2[1] + s2[2] + s2[3];
  const float inv2 = 1.0f / fmaxf(sqrtf(ss2), 1e-8f);

  ushortv4 o0, o1;
  o0[0]=f2bf(p20.x*inv2); o0[1]=f2bf(p20.y*inv2); o0[2]=f2bf(p20.z*inv2); o0[3]=f2bf(p20.w*inv2);
  o1[0]=f2bf(p21.x*inv2); o1[1]=f2bf(p21.y*inv2); o1[2]=f2bf(p21.z*inv2); o1[3]=f2bf(p21.w*inv2);
  *(ushortv4*)(p2nbf + k*DDIM + d0) = o0;
  *(ushortv4*)(p2nbf + k*DDIM + d1) = o1;
}

// ---------------------------------------------------------------------------
// k_final: wave-per-token, minimal live set (X[8]+va[8] ~55 VGPR, no prefetch
// array -> no spill).  P2n bf16 in LDS; fused ss+dot loop; scale computed by
// all lanes; gelu from still-live X; nt stores.  TLP (16 waves/CU) hides HBM.
// ---------------------------------------------------------------------------
__global__ __launch_bounds__(256, 4)
void k_final(const float* __restrict__ x, const unsigned short* __restrict__ p2nbf,
             const float* __restrict__ plt, const float* __restrict__ plb,
             float* __restrict__ out, int ntok)
{
  __shared__ unsigned short Pl[KC*DDIM];   // 32 KB
  const int t = threadIdx.x;
  const int wave = t >> 6, lane = t & 63;

  #pragma unroll
  for (int j = 0; j < 8; ++j){
    const int e = (j*256 + t)*8;
    *(ushortv8*)(Pl + e) = *(const ushortv8*)(p2nbf + e);
  }
  __syncthreads();

  const float tau   = __expf(plt[0]);
  const float alpha = 1.0f / (1.0f + __expf(-plb[0]));

  const int tl0 = wave*4;
  const int tok_base = blockIdx.x * TPB_C;
  const unsigned* Pw = (const unsigned*)Pl;

  #pragma unroll
  for (int i = 0; i < 4; ++i){
    const int tok = tok_base + tl0 + i;
    if (tok < ntok){
      const float* xp = x + (size_t)tok*DDIM + 4*lane;
      float4 X[8];
      #pragma unroll
      for (int j = 0; j < 8; ++j)
        X[j] = *(const float4*)(xp + j*256);

      float va[KC];
      #pragma unroll
      for (int k = 0; k < KC; ++k) va[k] = 0.f;
      float ss = 0.f;
      #pragma unroll
      for (int j = 0; j < 8; ++j){
        ss += X[j].x*X[j].x + X[j].y*X[j].y + X[j].z*X[j].z + X[j].w*X[j].w;
        #pragma unroll
        for (int k = 0; k < KC; ++k){
          uint2 u = *(const uint2*)(Pw + k*1024 + j*128 + 2*lane);
          va[k] += X[j].x*bflo(u.x) + X[j].y*bfhi(u.x)
                 + X[j].z*bflo(u.y) + X[j].w*bfhi(u.y);
        }
      }
      ss = wave_sum(ss);

      float mx = butterfly8(va, lane);
      mx = fmaxf(mx, __shfl_xor(mx, 1, 64));
      mx = fmaxf(mx, __shfl_xor(mx, 2, 64));
      mx = fmaxf(mx, __shfl_xor(mx, 4, 64));   // every lane: max over 8 clusters

      const float inv  = 1.0f / fmaxf(sqrtf(ss), 1e-8f);
      const float sv   = fminf(fmaxf(mx * inv, -1.0f), 1.0f);  // clip(max)==max(clip)
      const float dist = fminf(fmaxf(1.0f - sv, 0.0f), 2.0f);
      const float nov  = 1.0f - __expf(-tau * dist);
      float sc = 1.0f - alpha + alpha * nov;
      sc = fminf(fmaxf(sc, 0.1f), 10.0f);

      float* o = out + (size_t)tok*DDIM + 4*lane;
      #pragma unroll
      for (int j = 0; j < 8; ++j){
        float4 g;
        g.x = gelu_tanh(X[j].x*sc); g.y = gelu_tanh(X[j].y*sc);
        g.z = gelu_tanh(X[j].z*sc); g.w = gelu_tanh(X[j].w*sc);
        nt_store4(g, o + j*256);
      }
    }
  }
}

extern "C" void kernel_launch(void* const* d_in, const int* in_sizes, int n_in,
                              void* d_out, int out_size, void* d_ws, size_t ws_size,
                              hipStream_t stream)
{
  const float* x         = (const float*)d_in[0];
  const float* proto     = (const float*)d_in[1];
  const float* log_tau   = (const float*)d_in[2];
  const float* log_blend = (const float*)d_in[3];
  float* out = (float*)d_out;
  float* ws  = (float*)d_ws;

  const int ntok = in_sizes[0] / DDIM;   // 16384

  // ws layout (float units)
  unsigned short* p2nbf = (unsigned short*)(ws);           // 16384 bf16 = 8192 f
  float*          pcnts = ws + 8192;                       // nbA*8 (<= 8192)
  float*          csum  = ws + 16384;                      // 16384
  float*          ccnt  = ws + 32768;                      // 8 (pad to 16)
  unsigned short* part  = (unsigned short*)(ws + 32784);   // nbA*16384 bf16 (16B-aligned)

  const int nbA = (ntok + TPB_A - 1) / TPB_A;    // 1024
  const int nbC = (ntok + TPB_C - 1) / TPB_C;    // 1024

  k_assign<<<nbA, 256, 0, stream>>>(x, proto, part, pcnts, ntok);
  k_reduce<<<256, 256, 0, stream>>>(part, pcnts, csum, ccnt, nbA);
  k_mid   <<<KC,  256, 0, stream>>>(csum, ccnt, proto, p2nbf);
  k_final <<<nbC, 256, 0, stream>>>(x, p2nbf, log_tau, log_blend, out, ntok);
}

// Round 8
// 309.174 us; speedup vs baseline: 1.9785x; 1.9785x over previous
//
#include <hip/hip_runtime.h>

#define DDIM  2048
#define KC    8
#define TPB_A 16          // tokens per block, k_assign (4 waves x 4 tokens)
#define TPB_C 16          // tokens per block, k_final

typedef float nfloat4 __attribute__((ext_vector_type(4)));
typedef unsigned short ushortv8 __attribute__((ext_vector_type(8)));
typedef unsigned short ushortv4 __attribute__((ext_vector_type(4)));

__device__ __forceinline__ void nt_store4(const float4& v, float* p){
  nfloat4 nv; nv.x = v.x; nv.y = v.y; nv.z = v.z; nv.w = v.w;
  __builtin_nontemporal_store(nv, (nfloat4*)p);
}
__device__ __forceinline__ void nt_store_us4(const ushortv4& v, unsigned short* p){
  __builtin_nontemporal_store(v, (ushortv4*)p);
}
__device__ __forceinline__ ushortv8 nt_load_us8(const unsigned short* p){
  return __builtin_nontemporal_load((const ushortv8*)p);
}

// bf16 round-to-nearest-even pack; unpack = shift (exact)
__device__ __forceinline__ unsigned short f2bf(float f){
  unsigned u = __float_as_uint(f);
  u += 0x7fffu + ((u >> 16) & 1u);
  return (unsigned short)(u >> 16);
}
__device__ __forceinline__ float bf2f(unsigned short h){
  return __uint_as_float(((unsigned)h) << 16);
}
__device__ __forceinline__ float bflo(unsigned u){ return __uint_as_float(u << 16); }
__device__ __forceinline__ float bfhi(unsigned u){ return __uint_as_float(u & 0xffff0000u); }

__device__ __forceinline__ float wave_sum(float v){
  #pragma unroll
  for (int off = 32; off > 0; off >>= 1)
    v += __shfl_xor(v, off, 64);
  return v;   // broadcast: every lane holds the total
}

// Multi-value butterfly: sum v[0..7] across 64 lanes in 10 shuffles.
// On exit EVERY lane l holds the full wave-sum for cluster
// k = 4*(l&1) + 2*((l>>1)&1) + ((l>>2)&1).
__device__ __forceinline__ float butterfly8(float v[8], int t){
  {
    const bool h = (t & 1);
    #pragma unroll
    for (int j = 0; j < 4; ++j){
      float s    = h ? v[j]   : v[j+4];
      float keep = h ? v[j+4] : v[j];
      v[j] = keep + __shfl_xor(s, 1, 64);
    }
  }
  {
    const bool h = (t & 2);
    #pragma unroll
    for (int j = 0; j < 2; ++j){
      float s    = h ? v[j]   : v[j+2];
      float keep = h ? v[j+2] : v[j];
      v[j] = keep + __shfl_xor(s, 2, 64);
    }
  }
  {
    const bool h = (t & 4);
    float s    = h ? v[0] : v[1];
    float keep = h ? v[1] : v[0];
    v[0] = keep + __shfl_xor(s, 4, 64);
  }
  v[0] += __shfl_xor(v[0], 8, 64);
  v[0] += __shfl_xor(v[0], 16, 64);
  v[0] += __shfl_xor(v[0], 32, 64);
  return v[0];
}

__device__ __forceinline__ float gelu_tanh(float v){
  const float c = 0.7978845608028654f;
  float tt = c * v * (1.0f + 0.044715f * v * v);
  float e  = __expf(2.0f * tt);
  float th = 1.0f - 2.0f / (e + 1.0f);
  return 0.5f * v * (1.0f + th);
}

// ---------------------------------------------------------------------------
// k_pre: P_norm = proto / max(||proto||, 1e-12), stored bf16.  Block = cluster.
// (Separate tiny kernel on purpose: folding it into k_assign's prologue was a
//  confounder in the r3-r7 spill pathologies.)
// ---------------------------------------------------------------------------
__global__ __launch_bounds__(256)
void k_pre(const float* __restrict__ proto, unsigned short* __restrict__ pbf)
{
  const int k = blockIdx.x, t = threadIdx.x;
  const int wave = t >> 6, lane = t & 63;
  __shared__ float sred[4];
  const int d0 = 4*t, d1 = 1024 + 4*t;
  float4 a = *(const float4*)(proto + k*DDIM + d0);
  float4 b = *(const float4*)(proto + k*DDIM + d1);
  float ss = a.x*a.x + a.y*a.y + a.z*a.z + a.w*a.w
           + b.x*b.x + b.y*b.y + b.z*b.z + b.w*b.w;
  ss = wave_sum(ss);
  if (lane == 0) sred[wave] = ss;
  __syncthreads();
  ss = sred[0] + sred[1] + sred[2] + sred[3];
  const float inv = 1.0f / fmaxf(sqrtf(ss), 1e-12f);
  ushortv4 o0, o1;
  o0[0]=f2bf(a.x*inv); o0[1]=f2bf(a.y*inv); o0[2]=f2bf(a.z*inv); o0[3]=f2bf(a.w*inv);
  o1[0]=f2bf(b.x*inv); o1[1]=f2bf(b.y*inv); o1[2]=f2bf(b.z*inv); o1[3]=f2bf(b.w*inv);
  *(ushortv4*)(pbf + k*DDIM + d0) = o0;
  *(ushortv4*)(pbf + k*DDIM + d1) = o1;
}

// ---------------------------------------------------------------------------
// k_assign (round-2-proven hot loop): stage 1 = wave-per-token argmax with
// X/N serial prefetch chain (bounds the live window -- the codegen shape the
// allocator handles without spilling); stage 2 = thread-per-8-dims segment
// accumulate (x re-read L2/L3-hot), nt bf16 partial stores.
// ---------------------------------------------------------------------------
__global__ __launch_bounds__(256, 4)
void k_assign(const float* __restrict__ x, const unsigned short* __restrict__ pbf,
              unsigned short* __restrict__ part, float* __restrict__ pcnts, int ntok)
{
  __shared__ unsigned short Pl[KC*DDIM];   // 32 KB bf16 normalized prototypes
  __shared__ int asg[TPB_A];

  const int t = threadIdx.x;
  const int wave = t >> 6, lane = t & 63;

  // stage P into LDS: 8 x 16B coalesced per thread
  #pragma unroll
  for (int j = 0; j < 8; ++j){
    const int e = (j*256 + t)*8;
    *(ushortv8*)(Pl + e) = *(const ushortv8*)(pbf + e);
  }
  __syncthreads();

  const int tok_base = blockIdx.x * TPB_A;

  // ---- stage 1: wave w -> tokens w*4 .. w*4+3 ----
  {
    const int tl0 = wave*4;
    float4 X[8], N[8];
    int tok = tok_base + tl0;
    if (tok < ntok){
      #pragma unroll
      for (int j = 0; j < 8; ++j)
        X[j] = *(const float4*)(x + (size_t)tok*DDIM + j*256 + 4*lane);
    }
    #pragma unroll
    for (int i = 0; i < 4; ++i){
      const int tok_i = tok_base + tl0 + i;
      const bool ldn = (i < 3) && (tok_i + 1 < ntok);
      if (ldn){
        #pragma unroll
        for (int j = 0; j < 8; ++j)
          N[j] = *(const float4*)(x + (size_t)(tok_i+1)*DDIM + j*256 + 4*lane);
      }
      if (tok_i < ntok){
        float v[KC];
        #pragma unroll
        for (int k = 0; k < KC; ++k){
          float s = 0.f;
          #pragma unroll
          for (int j = 0; j < 8; ++j){
            uint2 u = *(const uint2*)((const unsigned*)Pl + k*1024 + j*128 + 2*lane);
            s += X[j].x*bflo(u.x) + X[j].y*bfhi(u.x)
               + X[j].z*bflo(u.y) + X[j].w*bfhi(u.y);
          }
          v[k] = s;
        }
        float bv = butterfly8(v, lane);
        int   bi = ((lane&1)<<2) | (lane&2) | ((lane>>2)&1);
        #pragma unroll
        for (int off = 1; off < 8; off <<= 1){
          float ov = __shfl_xor(bv, off, 64);
          int   oi = __shfl_xor(bi, off, 64);
          if (ov > bv || (ov == bv && oi < bi)){ bv = ov; bi = oi; }  // first-index ties
        }
        if (lane == 0) asg[tl0 + i] = bi;
      }
      if (ldn){
        #pragma unroll
        for (int j = 0; j < 8; ++j) X[j] = N[j];
      }
    }
  }
  __syncthreads();

  // ---- stage 2: thread t owns dims {4t..4t+3, 1024+4t..+3} ----
  const int d0 = 4*t, d1 = 1024 + 4*t;
  float4 acc0[KC], acc1[KC];
  float cnt[KC];
  #pragma unroll
  for (int k = 0; k < KC; ++k){
    acc0[k] = make_float4(0.f,0.f,0.f,0.f);
    acc1[k] = make_float4(0.f,0.f,0.f,0.f);
    cnt[k] = 0.f;
  }
  #pragma unroll
  for (int i = 0; i < TPB_A; ++i){
    const int tok = tok_base + i;
    if (tok < ntok){
      const int a = asg[i];   // block-uniform -> scalar branch
      float4 xa = *(const float4*)(x + (size_t)tok*DDIM + d0);
      float4 xb = *(const float4*)(x + (size_t)tok*DDIM + d1);
      #pragma unroll
      for (int k = 0; k < KC; ++k){
        if (a == k){
          acc0[k].x += xa.x; acc0[k].y += xa.y; acc0[k].z += xa.z; acc0[k].w += xa.w;
          acc1[k].x += xb.x; acc1[k].y += xb.y; acc1[k].z += xb.z; acc1[k].w += xb.w;
          cnt[k] += 1.f;
        }
      }
    }
  }
  // nt stores: part is write-once/read-once — keep it out of L3 so x stays resident
  unsigned short* dst = part + (size_t)blockIdx.x * (KC*DDIM);
  #pragma unroll
  for (int k = 0; k < KC; ++k){
    ushortv4 o0, o1;
    o0[0]=f2bf(acc0[k].x); o0[1]=f2bf(acc0[k].y); o0[2]=f2bf(acc0[k].z); o0[3]=f2bf(acc0[k].w);
    o1[0]=f2bf(acc1[k].x); o1[1]=f2bf(acc1[k].y); o1[2]=f2bf(acc1[k].z); o1[3]=f2bf(acc1[k].w);
    nt_store_us4(o0, dst + k*DDIM + d0);
    nt_store_us4(o1, dst + k*DDIM + d1);
  }
  if (t == 0){
    #pragma unroll
    for (int k = 0; k < KC; ++k) pcnts[blockIdx.x*KC + k] = cnt[k];
  }
}

// ---------------------------------------------------------------------------
// k_reduce: single-stage — nbA bf16 partials -> fp32 column sums (+ counts).
// grid = 256: block (k = bid>>5, s = bid&31) owns a 64-dim slice of cluster k.
// 32 thread-groups each sum a b-stripe; LDS combine; 64 threads finalize.
// (Proven correct in r6/r7; replaces round 2's two-stage reduce chain.)
// ---------------------------------------------------------------------------
__global__ __launch_bounds__(256)
void k_reduce(const unsigned short* __restrict__ part, const float* __restrict__ pcnts,
              float* __restrict__ csum, float* __restrict__ ccnt, int nbA)
{
  const int k = blockIdx.x >> 5;       // 0..7
  const int s = blockIdx.x & 31;       // 0..31
  const int t = threadIdx.x;
  const int slot = t & 7;              // 8 x 8-elem slots cover the 64-dim slice
  const int grp  = t >> 3;             // 32 b-stripes

  __shared__ float cmb[32][8][8];      // [grp][slot][j] = 8 KB
  __shared__ float credn[4];

  const size_t ebase = (size_t)k*DDIM + s*64 + slot*8;
  float a[8] = {0.f,0.f,0.f,0.f,0.f,0.f,0.f,0.f};
  for (int b = grp; b < nbA; b += 32){
    ushortv8 v = nt_load_us8(part + (size_t)b*(KC*DDIM) + ebase);
    #pragma unroll
    for (int j = 0; j < 8; ++j) a[j] += bf2f(v[j]);
  }
  #pragma unroll
  for (int j = 0; j < 8; ++j) cmb[grp][slot][j] = a[j];

  // counts (only s==0 blocks)
  float c = 0.f;
  if (s == 0){
    for (int b = t; b < nbA; b += 256) c += pcnts[b*KC + k];
    c = wave_sum(c);
    if ((t & 63) == 0) credn[t >> 6] = c;
  }
  __syncthreads();

  if (t < 64){
    const int slot2 = t >> 3, j = t & 7;
    float sum = 0.f;
    #pragma unroll
    for (int g = 0; g < 32; ++g) sum += cmb[g][slot2][j];
    csum[(size_t)k*DDIM + s*64 + slot2*8 + j] = sum;
  }
  if (s == 0 && t == 0)
    ccnt[k] = credn[0] + credn[1] + credn[2] + credn[3];
}

// ---------------------------------------------------------------------------
// k_mid: csum -> centroid (count>0 else proto) -> normalize(1e-12) -> momentum
// -> normalize(1e-8) -> p2n bf16.  Block = cluster.
// ---------------------------------------------------------------------------
__global__ __launch_bounds__(256)
void k_mid(const float* __restrict__ csum, const float* __restrict__ ccnt,
           const float* __restrict__ proto, unsigned short* __restrict__ p2nbf)
{
  const int k = blockIdx.x, t = threadIdx.x;
  const int wave = t >> 6, lane = t & 63;
  __shared__ float s1[4], s2[4];
  const int d0 = 4*t, d1 = 1024 + 4*t;

  float4 a = *(const float4*)(csum + k*DDIM + d0);
  float4 b = *(const float4*)(csum + k*DDIM + d1);
  const float c = ccnt[k];

  float4 pr0 = *(const float4*)(proto + k*DDIM + d0);
  float4 pr1 = *(const float4*)(proto + k*DDIM + d1);

  float4 c0, c1;
  if (c > 0.f){
    const float inv = 1.0f / fmaxf(c, 1.0f);
    c0.x=a.x*inv; c0.y=a.y*inv; c0.z=a.z*inv; c0.w=a.w*inv;
    c1.x=b.x*inv; c1.y=b.y*inv; c1.z=b.z*inv; c1.w=b.w*inv;
  } else { c0 = pr0; c1 = pr1; }

  float ss = c0.x*c0.x + c0.y*c0.y + c0.z*c0.z + c0.w*c0.w
           + c1.x*c1.x + c1.y*c1.y + c1.z*c1.z + c1.w*c1.w;
  ss = wave_sum(ss);
  if (lane == 0) s1[wave] = ss;
  __syncthreads();
  ss = s1[0] + s1[1] + s1[2] + s1[3];
  const float invc = 1.0f / fmaxf(sqrtf(ss), 1e-12f);

  const float m = 0.999f, om = 1.0f - 0.999f;
  float4 p20, p21;
  p20.x = m*pr0.x + om*c0.x*invc; p20.y = m*pr0.y + om*c0.y*invc;
  p20.z = m*pr0.z + om*c0.z*invc; p20.w = m*pr0.w + om*c0.w*invc;
  p21.x = m*pr1.x + om*c1.x*invc; p21.y = m*pr1.y + om*c1.y*invc;
  p21.z = m*pr1.z + om*c1.z*invc; p21.w = m*pr1.w + om*c1.w*invc;

  float ss2 = p20.x*p20.x + p20.y*p20.y + p20.z*p20.z + p20.w*p20.w
            + p21.x*p21.x + p21.y*p21.y + p21.z*p21.z + p21.w*p21.w;
  ss2 = wave_sum(ss2);
  if (lane == 0) s2[wave] = ss2;
  __syncthreads();
  ss2 = s2[0] + s2[1] + s2[2] + s2[3];
  const float inv2 = 1.0f / fmaxf(sqrtf(ss2), 1e-8f);

  ushortv4 o0, o1;
  o0[0]=f2bf(p20.x*inv2); o0[1]=f2bf(p20.y*inv2); o0[2]=f2bf(p20.z*inv2); o0[3]=f2bf(p20.w*inv2);
  o1[0]=f2bf(p21.x*inv2); o1[1]=f2bf(p21.y*inv2); o1[2]=f2bf(p21.z*inv2); o1[3]=f2bf(p21.w*inv2);
  *(ushortv4*)(p2nbf + k*DDIM + d0) = o0;
  *(ushortv4*)(p2nbf + k*DDIM + d1) = o1;
}

// ---------------------------------------------------------------------------
// k_final (round-2-proven hot loop): wave-per-token with X/N serial prefetch
// chain; P2n bf16 in LDS; k-outer dot with scalar accumulator; scale computed
// by all lanes (no serial section, no loop barriers); gelu + nt stores.
// ---------------------------------------------------------------------------
__global__ __launch_bounds__(256, 4)
void k_final(const float* __restrict__ x, const unsigned short* __restrict__ p2nbf,
             const float* __restrict__ plt, const float* __restrict__ plb,
             float* __restrict__ out, int ntok)
{
  __shared__ unsigned short Pl[KC*DDIM];   // 32 KB
  const int t = threadIdx.x;
  const int wave = t >> 6, lane = t & 63;

  #pragma unroll
  for (int j = 0; j < 8; ++j){
    const int e = (j*256 + t)*8;
    *(ushortv8*)(Pl + e) = *(const ushortv8*)(p2nbf + e);
  }
  __syncthreads();

  const float tau   = __expf(plt[0]);
  const float alpha = 1.0f / (1.0f + __expf(-plb[0]));

  const int tl0 = wave*4;
  const int tok_base = blockIdx.x * TPB_C;
  float4 X[8], N[8];
  {
    const int tok = tok_base + tl0;
    if (tok < ntok){
      #pragma unroll
      for (int j = 0; j < 8; ++j)
        X[j] = *(const float4*)(x + (size_t)tok*DDIM + j*256 + 4*lane);
    }
  }
  #pragma unroll
  for (int i = 0; i < 4; ++i){
    const int tok_i = tok_base + tl0 + i;
    const bool ldn = (i < 3) && (tok_i + 1 < ntok);
    if (ldn){
      #pragma unroll
      for (int j = 0; j < 8; ++j)
        N[j] = *(const float4*)(x + (size_t)(tok_i+1)*DDIM + j*256 + 4*lane);
    }
    if (tok_i < ntok){
      float ss = 0.f;
      #pragma unroll
      for (int j = 0; j < 8; ++j)
        ss += X[j].x*X[j].x + X[j].y*X[j].y + X[j].z*X[j].z + X[j].w*X[j].w;
      ss = wave_sum(ss);

      float v[KC];
      #pragma unroll
      for (int k = 0; k < KC; ++k){
        float s = 0.f;
        #pragma unroll
        for (int j = 0; j < 8; ++j){
          uint2 u = *(const uint2*)((const unsigned*)Pl + k*1024 + j*128 + 2*lane);
          s += X[j].x*bflo(u.x) + X[j].y*bfhi(u.x)
             + X[j].z*bflo(u.y) + X[j].w*bfhi(u.y);
        }
        v[k] = s;
      }
      float mx = butterfly8(v, lane);
      mx = fmaxf(mx, __shfl_xor(mx, 1, 64));
      mx = fmaxf(mx, __shfl_xor(mx, 2, 64));
      mx = fmaxf(mx, __shfl_xor(mx, 4, 64));   // every lane: max over 8 clusters

      const float inv  = 1.0f / fmaxf(sqrtf(ss), 1e-8f);
      const float s    = fminf(fmaxf(mx * inv, -1.0f), 1.0f);  // clip(max)==max(clip)
      const float dist = fminf(fmaxf(1.0f - s, 0.0f), 2.0f);
      const float nov  = 1.0f - __expf(-tau * dist);
      float sc = 1.0f - alpha + alpha * nov;
      sc = fminf(fmaxf(sc, 0.1f), 10.0f);

      float* o = out + (size_t)tok_i*DDIM;
      #pragma unroll
      for (int j = 0; j < 8; ++j){
        float4 g;
        g.x = gelu_tanh(X[j].x*sc); g.y = gelu_tanh(X[j].y*sc);
        g.z = gelu_tanh(X[j].z*sc); g.w = gelu_tanh(X[j].w*sc);
        nt_store4(g, o + j*256 + 4*lane);
      }
    }
    if (ldn){
      #pragma unroll
      for (int j = 0; j < 8; ++j) X[j] = N[j];
    }
  }
}

extern "C" void kernel_launch(void* const* d_in, const int* in_sizes, int n_in,
                              void* d_out, int out_size, void* d_ws, size_t ws_size,
                              hipStream_t stream)
{
  const float* x         = (const float*)d_in[0];
  const float* proto     = (const float*)d_in[1];
  const float* log_tau   = (const float*)d_in[2];
  const float* log_blend = (const float*)d_in[3];
  float* out = (float*)d_out;
  float* ws  = (float*)d_ws;

  const int ntok = in_sizes[0] / DDIM;   // 16384

  // ws layout (float units)
  unsigned short* pbf   = (unsigned short*)(ws);           // 16384 bf16 = 8192 f
  unsigned short* p2nbf = (unsigned short*)(ws + 8192);    // 16384 bf16
  float*          pcnts = ws + 16384;                      // nbA*8 (<= 8192)
  float*          csum  = ws + 24576;                      // 16384
  float*          ccnt  = ws + 40960;                      // 8 (pad to 16)
  unsigned short* part  = (unsigned short*)(ws + 40976);   // nbA*16384 bf16 (16B-aligned)

  const int nbA = (ntok + TPB_A - 1) / TPB_A;    // 1024
  const int nbC = (ntok + TPB_C - 1) / TPB_C;    // 1024

  k_pre   <<<KC,  256, 0, stream>>>(proto, pbf);
  k_assign<<<nbA, 256, 0, stream>>>(x, pbf, part, pcnts, ntok);
  k_reduce<<<256, 256, 0, stream>>>(part, pcnts, csum, ccnt, nbA);
  k_mid   <<<KC,  256, 0, stream>>>(csum, ccnt, proto, p2nbf);
  k_final <<<nbC, 256, 0, stream>>>(x, p2nbf, log_tau, log_blend, out, ntok);
}